// Round 20
// baseline (47.321 us; speedup 1.0000x reference)
//
#include <hip/hip_runtime.h>

// GNN1: drug-relation GNN layer, MI355X (gfx950).  r19 structure + w2sum
// folded into gnn_a4x (prep's serial W2 pass deleted; W2 reads overlap GEMM).
//   prep_kernel  : b2s[k] + GLOBAL rela hi/lo bf16 A-frag table. 56 blocks.
//   gnn_a4x      : ONE 512-thread block per (drug, e-half). In-block w2sum
//                  (32 W2-row sums, 16 thr/row + shfl). S[r,e] = sum_d
//                  rela[r,d]*(drug[d]*W1[d,e]); GEMM once per e-half;
//                  S-half[200][32] LDS; full-k b1-epilogue -> scoresA/B.
//   softgather   : softmax over K (A+B+b2s), deterministic compaction,
//                  pipelined ent gather, final linear -> y.
//   bn_kernel    : BatchNorm1d (training stats) over N=846 -> out.
// LESSON (r17): no per-block __threadfence handoff on MI355X — device-scope
// release fences serialize via cross-XCD L2 writebacks (47->410 us).

#define NDRUG 846
#define KNB   1024
#define NREL  200
#define BN_EPS 1e-5f

#define NRELT 13312                      // 13 mt * 2 ss * 64 lane * 8 j
#define NRELB (NRELT/256)                // 52 rela-split blocks

typedef __attribute__((ext_vector_type(8))) short short8;
typedef __attribute__((ext_vector_type(4))) float f32x4;

__device__ __forceinline__ unsigned short f2bf(float x){
    unsigned u = __float_as_uint(x);
    unsigned r = u + 0x7fffu + ((u >> 16) & 1u);
    return (unsigned short)(r >> 16);
}
__device__ __forceinline__ float bf2f(unsigned short h){
    return __uint_as_float(((unsigned)h) << 16);
}

// blocks [0,4): b2 row sums; [4, 4+NRELB): rela A-frag split
__global__ void prep_kernel(const float* __restrict__ b2,
                            const float* __restrict__ rela_table,
                            float* __restrict__ b2s,
                            unsigned short* __restrict__ relah,
                            unsigned short* __restrict__ relal){
    int b = blockIdx.x;
    int t = threadIdx.x;
    if (b < 4){
        int k = b*256 + t;
        const float4* p = (const float4*)(b2 + (size_t)k*64);
        float s = 0.f;
        #pragma unroll
        for (int i = 0; i < 16; ++i){ float4 v = p[i]; s += v.x+v.y+v.z+v.w; }
        b2s[k] = s;
    } else {
        // rela hi/lo split in A-fragment layout:
        // idx = ((mt*2+ss)*64 + lane)*8 + j ; row = mt*16+(lane&15) clamp 199,
        // d = ss*32 + (lane>>4)*8 + j
        int idx = (b - 4)*256 + t;                     // [0, NRELT)
        int j  = idx & 7;
        int ln = (idx >> 3) & 63;
        int ss = (idx >> 9) & 1;
        int mt = idx >> 10;
        int r = mt*16 + (ln & 15); if (r > 199) r = 199;
        int d = ss*32 + ((ln >> 4) << 3) + j;
        float v = rela_table[r*64 + d];
        unsigned short h = (unsigned short)(__float_as_uint(v) >> 16);  // trunc hi
        relah[idx] = h;
        relal[idx] = f2bf(v - bf2f(h));
    }
}

__global__ __launch_bounds__(512) void gnn_a4x(
    const float* __restrict__ drug_table, const unsigned short* __restrict__ relah,
    const unsigned short* __restrict__ relal,
    const float* __restrict__ W1,         const float* __restrict__ b1,
    const float* __restrict__ W2,         const int* __restrict__ drug_name,
    const int* __restrict__ adj_rel,
    float* __restrict__ scoresA,          float* __restrict__ scoresB)
{
    __shared__ __align__(16) float sS[6400];    // S-half[200][32], XOR-swizzled
    __shared__ __align__(16) float w2s[32];
    unsigned short* Bh = (unsigned short*)sS;          // overlay: dead after hoist
    unsigned short* Bl = (unsigned short*)(sS + 1024); // 4KB each

    const int t = threadIdx.x;
    const int lane = t & 63;
    const int w = t >> 6;                  // 8 waves
    const int lg = lane >> 4;
    const int l15 = lane & 15;
    const int n = blockIdx.x;
    const int ehalf = blockIdx.y;
    const int e_base = ehalf << 5;

    // independent global loads first: epilogue indices + mi=0 A-frags
    const int* arel = adj_rel + (size_t)n*KNB;
    int rr8[8];
    #pragma unroll
    for (int pass = 0; pass < 8; ++pass)
        rr8[pass] = arel[pass*128 + w*16 + (lane >> 2)];

    const short8* Ah_t = (const short8*)relah;
    const short8* Al_t = (const short8*)relal;
    short8 Ah0a = Ah_t[(w*2+0)*64 + lane];
    short8 Ah1a = Ah_t[(w*2+1)*64 + lane];
    short8 Al0a = Al_t[(w*2+0)*64 + lane];
    short8 Al1a = Al_t[(w*2+1)*64 + lane];

    // in-block w2sum: w2s[eo] = sum_j W2[n, e_base+eo, j]; 16 threads per row
    {
        int eo = t >> 4, q16 = t & 15;
        const f32x4* W2p = (const f32x4*)(W2 + (size_t)n*4096
                                          + (size_t)(e_base + eo)*64 + q16*4);
        f32x4 v = *W2p;
        float s = v[0]+v[1]+v[2]+v[3];
        s += __shfl_xor(s, 1);
        s += __shfl_xor(s, 2);
        s += __shfl_xor(s, 4);
        s += __shfl_xor(s, 8);
        if (q16 == 0) w2s[eo] = s;
    }

    // stage half of (drug[d]*W1[d,:]) -> hi/lo bf16, fragment-linear.
    // drug values loaded directly (16 adjacent threads share one d -> L1
    // broadcast); no LDS round-trip.
    {
        const int dn = drug_name[n];
        const float* drugp = drug_table + (size_t)dn*64;
        const float* W1n = W1 + (size_t)n*4096;
        #pragma unroll
        for (int p = 0; p < 4; ++p){
            int idx = p*512 + t;               // 2048 elems: d = idx>>5, eo = idx&31
            int d = idx >> 5, eo = idx & 31;
            float v = W1n[d*64 + e_base + eo] * drugp[d];
            int ss = d >> 5, j = d & 7, lgb = (d >> 3) & 3, nn = eo >> 4;
            int ln = (lgb << 4) | (eo & 15);
            int dst = (((ss<<1)|nn)*64 + ln)*8 + j;
            unsigned short h = (unsigned short)(__float_as_uint(v) >> 16);  // trunc hi
            Bh[dst] = h;
            Bl[dst] = f2bf(v - bf2f(h));
        }
    }
    __syncthreads();   // staging + w2s visible

    // hoist the 4 B-fragment pairs (frag-groups: ss*2+nn)
    short8 bhr[4], blr[4];
    #pragma unroll
    for (int f = 0; f < 4; ++f){
        bhr[f] = *(const short8*)&Bh[(f*64 + lane)*8];
        blr[f] = *(const short8*)&Bl[(f*64 + lane)*8];
    }
    __syncthreads();   // Bh/Bl dead; sS writable

    // GEMM mi=0 (mt = w, always valid) with prefetched A-frags
    {
        f32x4 acc[2] = {};
        #pragma unroll
        for (int nn = 0; nn < 2; ++nn){
            acc[nn] = __builtin_amdgcn_mfma_f32_16x16x32_bf16(Ah0a, bhr[nn],   acc[nn], 0,0,0);
            acc[nn] = __builtin_amdgcn_mfma_f32_16x16x32_bf16(Ah0a, blr[nn],   acc[nn], 0,0,0);
            acc[nn] = __builtin_amdgcn_mfma_f32_16x16x32_bf16(Al0a, bhr[nn],   acc[nn], 0,0,0);
            acc[nn] = __builtin_amdgcn_mfma_f32_16x16x32_bf16(Ah1a, bhr[2+nn], acc[nn], 0,0,0);
            acc[nn] = __builtin_amdgcn_mfma_f32_16x16x32_bf16(Ah1a, blr[2+nn], acc[nn], 0,0,0);
            acc[nn] = __builtin_amdgcn_mfma_f32_16x16x32_bf16(Al1a, bhr[2+nn], acc[nn], 0,0,0);
        }
        // park: word(r,eo) = r*32 + ((eo>>2 ^ (r&7))<<2) + (eo&3)
        int rb = w*16 + (lg<<2);
        #pragma unroll
        for (int nn = 0; nn < 2; ++nn){
            int eo = (nn<<4) | l15;
            int slot = eo >> 2, wrd = eo & 3;
            #pragma unroll
            for (int q = 0; q < 4; ++q){
                int r = rb + q;
                sS[r*32 + ((slot ^ (r & 7))<<2) + wrd] = acc[nn][q];  // r < 128 < 200
            }
        }
    }
    // GEMM mi=1 (mt = w+8; valid for w<5)
    {
        int mt = w + 8;
        if (mt < 13){
            short8 Ah0 = Ah_t[(mt*2+0)*64 + lane];
            short8 Ah1 = Ah_t[(mt*2+1)*64 + lane];
            short8 Al0 = Al_t[(mt*2+0)*64 + lane];
            short8 Al1 = Al_t[(mt*2+1)*64 + lane];
            f32x4 acc[2] = {};
            #pragma unroll
            for (int nn = 0; nn < 2; ++nn){
                acc[nn] = __builtin_amdgcn_mfma_f32_16x16x32_bf16(Ah0, bhr[nn],   acc[nn], 0,0,0);
                acc[nn] = __builtin_amdgcn_mfma_f32_16x16x32_bf16(Ah0, blr[nn],   acc[nn], 0,0,0);
                acc[nn] = __builtin_amdgcn_mfma_f32_16x16x32_bf16(Al0, bhr[nn],   acc[nn], 0,0,0);
                acc[nn] = __builtin_amdgcn_mfma_f32_16x16x32_bf16(Ah1, bhr[2+nn], acc[nn], 0,0,0);
                acc[nn] = __builtin_amdgcn_mfma_f32_16x16x32_bf16(Ah1, blr[2+nn], acc[nn], 0,0,0);
                acc[nn] = __builtin_amdgcn_mfma_f32_16x16x32_bf16(Al1, bhr[2+nn], acc[nn], 0,0,0);
            }
            int rb = mt*16 + (lg<<2);
            #pragma unroll
            for (int nn = 0; nn < 2; ++nn){
                int eo = (nn<<4) | l15;
                int slot = eo >> 2, wrd = eo & 3;
                #pragma unroll
                for (int q = 0; q < 4; ++q){
                    int r = rb + q;
                    if (r < 200)
                        sS[r*32 + ((slot ^ (r & 7))<<2) + wrd] = acc[nn][q];
                }
            }
        }
    }
    __syncthreads();   // sS ready

    // epilogue over FULL k-range: partial score = sum_{e in half}
    // relu(S[arel[k],e] + b1[k,e]) * w2s[e];  4 lanes per k, 8 e's per lane;
    // 8 passes x 128 k per pass.
    float* sout = (ehalf ? scoresB : scoresA) + (size_t)n*KNB;
    const int ec = lane & 3;
    f32x4 w2r[2];
    #pragma unroll
    for (int j = 0; j < 2; ++j) w2r[j] = *(const f32x4*)&w2s[ec*8 + j*4];

    #pragma unroll 2
    for (int pass = 0; pass < 8; ++pass){
        int k = pass*128 + w*16 + (lane >> 2);
        int rr = rr8[pass];
        const float* b1p = b1 + (size_t)k*64 + e_base + ec*8;
        float sc = 0.f;
        #pragma unroll
        for (int j = 0; j < 2; ++j){
            int slot = ec*2 + j;
            f32x4 s4 = *(const f32x4*)&sS[rr*32 + ((slot ^ (rr & 7))<<2)];
            f32x4 bq = *(const f32x4*)(b1p + 4*j);
            #pragma unroll
            for (int q = 0; q < 4; ++q)
                sc += fmaxf(s4[q] + bq[q], 0.f) * w2r[j][q];
        }
        sc += __shfl_xor(sc, 1);
        sc += __shfl_xor(sc, 2);
        if (ec == 0) sout[k] = sc;
    }
}

__global__ __launch_bounds__(256,6) void softgather(
    const float* __restrict__ scoresA,  const float* __restrict__ scoresB,
    const float* __restrict__ b2s,
    const int* __restrict__ adj_tail,   const float* __restrict__ ent_table,
    const float* __restrict__ drug_table, const int* __restrict__ drug_name,
    const float* __restrict__ lin_w,    const float* __restrict__ lin_b,
    float* __restrict__ y_out)
{
    __shared__ float sE[KNB];
    __shared__ int list[KNB];
    __shared__ int segc[17];
    __shared__ float red[256];
    __shared__ float wepart[4][64];
    __shared__ float de[128];

    const int t = threadIdx.x;
    const int lane = t & 63;
    const int w = t >> 6;
    const int n = blockIdx.x;

    float dpre = 0.f;
    if (t < 64) dpre = drug_table[(size_t)drug_name[n]*64 + t];

    const float* sgA = scoresA + (size_t)n*KNB;
    const float* sgB = scoresB + (size_t)n*KNB;
    float sv[4]; float mx = -1e30f;
    #pragma unroll
    for (int i = 0; i < 4; ++i){
        int k = t + (i<<8);
        sv[i] = sgA[k] + sgB[k] + b2s[k];
        mx = fmaxf(mx, sv[i]);
    }
    #pragma unroll
    for (int off = 1; off < 64; off <<= 1) mx = fmaxf(mx, __shfl_xor(mx, off, 64));
    if (lane == 0) red[w] = mx;
    __syncthreads();
    mx = fmaxf(fmaxf(red[0], red[1]), fmaxf(red[2], red[3]));
    float ei[4]; float ps = 0.f;
    #pragma unroll
    for (int i = 0; i < 4; ++i){
        ei[i] = __expf(sv[i] - mx);
        sE[t + (i<<8)] = ei[i];
        ps += ei[i];
    }
    #pragma unroll
    for (int off = 1; off < 64; off <<= 1) ps += __shfl_xor(ps, off, 64);
    if (lane == 0) red[8 + w] = ps;
    __syncthreads();
    const float inv = 1.f / (red[8]+red[9]+red[10]+red[11]);

    // deterministic compaction of nonzero-weight k's (ordered by k)
    unsigned long long bal[4]; int pos[4];
    #pragma unroll
    for (int i = 0; i < 4; ++i){
        bool nz = (ei[i] != 0.f);
        bal[i] = __ballot(nz);
        pos[i] = (int)__popcll(bal[i] & ((1ull << lane) - 1ull));
        if (lane == 0) segc[i*4 + w] = (int)__popcll(bal[i]);
    }
    __syncthreads();
    if (t == 0){
        int acc = 0;
        #pragma unroll
        for (int s = 0; s < 16; ++s){ int c = segc[s]; segc[s] = acc; acc += c; }
        segc[16] = acc;
    }
    __syncthreads();
    #pragma unroll
    for (int i = 0; i < 4; ++i){
        if (ei[i] != 0.f)
            list[segc[i*4 + w] + pos[i]] = (i<<8) + (w<<6) + lane;
    }
    const int C = segc[16];
    __syncthreads();

    // pipelined gather over compacted list (wave-strided)
    const int* atail = adj_tail + (size_t)n*KNB;
    float awe = 0.f;
    {
        int j = w;
        float ev0 = 0.f, row0 = 0.f;
        if (j < C){
            int k0 = list[j];
            ev0 = sE[k0];
            row0 = ent_table[(size_t)atail[k0]*64 + lane];
        }
        while (j < C){
            int jn = j + 4;
            float ev1 = 0.f, row1 = 0.f;
            if (jn < C){
                int k1 = list[jn];
                ev1 = sE[k1];
                row1 = ent_table[(size_t)atail[k1]*64 + lane];
            }
            awe += ev0 * row0;
            ev0 = ev1; row0 = row1; j = jn;
        }
    }
    wepart[w][lane] = awe;
    __syncthreads();
    if (t < 64){
        de[t]    = (wepart[0][t]+wepart[1][t]+wepart[2][t]+wepart[3][t]) * inv;
        de[64+t] = dpre;
    }
    __syncthreads();

    float yp = 0.f;
    #pragma unroll
    for (int ii = 0; ii < 32; ++ii){
        int i = w*32 + ii;
        yp += de[i] * lin_w[lane*128 + i];
    }
    red[t] = yp;
    __syncthreads();
    if (t < 64){
        float yv = lin_b[t] + red[t] + red[64+t] + red[128+t] + red[192+t];
        y_out[(size_t)n*64 + t] = fmaxf(yv, 0.f);
    }
}

__global__ void bn_kernel(const float* __restrict__ y, const float* __restrict__ bn_w,
                          const float* __restrict__ bn_b, float* __restrict__ out){
    __shared__ float r1[4], r2[4];
    const int j = blockIdx.x;
    const int t = threadIdx.x;
    float s1 = 0.f, s2 = 0.f;
    for (int i = t; i < NDRUG; i += 256){
        float v = y[(size_t)i*64 + j];
        s1 += v; s2 += v*v;
    }
    #pragma unroll
    for (int off = 1; off < 64; off <<= 1){
        s1 += __shfl_xor(s1, off, 64);
        s2 += __shfl_xor(s2, off, 64);
    }
    int w = t >> 6, lane = t & 63;
    if (lane == 0){ r1[w] = s1; r2[w] = s2; }
    __syncthreads();
    s1 = r1[0]+r1[1]+r1[2]+r1[3];
    s2 = r2[0]+r2[1]+r2[2]+r2[3];
    float mean = s1 * (1.f/NDRUG);
    float var  = s2 * (1.f/NDRUG) - mean*mean;   // biased (training-mode) variance
    float sc = rsqrtf(var + BN_EPS) * bn_w[j];
    float sh = bn_b[j] - mean*sc;
    for (int i = t; i < NDRUG; i += 256)
        out[(size_t)i*64 + j] = y[(size_t)i*64 + j]*sc + sh;
}

extern "C" void kernel_launch(void* const* d_in, const int* in_sizes, int n_in,
                              void* d_out, int out_size, void* d_ws, size_t ws_size,
                              hipStream_t stream) {
    const float* drug_table = (const float*)d_in[0];
    const float* rela_table = (const float*)d_in[1];
    const float* ent_table  = (const float*)d_in[2];
    const float* W1    = (const float*)d_in[3];
    const float* b1    = (const float*)d_in[4];
    const float* W2    = (const float*)d_in[5];
    const float* b2    = (const float*)d_in[6];
    const float* lin_w = (const float*)d_in[7];
    const float* lin_b = (const float*)d_in[8];
    const float* bn_w  = (const float*)d_in[9];
    const float* bn_b  = (const float*)d_in[10];
    const int* drug_name = (const int*)d_in[11];
    const int* adj_tail  = (const int*)d_in[12];
    const int* adj_rel   = (const int*)d_in[13];
    float* out = (float*)d_out;

    float* b2s     = (float*)d_ws;                  // [1024]
    float* yb      = b2s + KNB;                     // [846*64]
    float* scoresA = yb + NDRUG*64;                 // [846*1024]
    float* scoresB = scoresA + (size_t)NDRUG*KNB;   // [846*1024]
    unsigned short* relah = (unsigned short*)(scoresB + (size_t)NDRUG*KNB); // [13312]
    unsigned short* relal = relah + NRELT;                                  // [13312]

    prep_kernel<<<4 + NRELB, 256, 0, stream>>>(b2, rela_table, b2s, relah, relal);
    gnn_a4x<<<dim3(NDRUG,2), 512, 0, stream>>>(drug_table, relah, relal, W1, b1,
                                               W2, drug_name, adj_rel,
                                               scoresA, scoresB);
    softgather<<<NDRUG, 256, 0, stream>>>(scoresA, scoresB, b2s, adj_tail, ent_table,
                                          drug_table, drug_name, lin_w, lin_b, yb);
    bn_kernel<<<64, 256, 0, stream>>>(yb, bn_w, bn_b, out);
}

// Round 21
// 46.070 us; speedup vs baseline: 1.0272x; 1.0272x over previous
//
#include <hip/hip_runtime.h>

// GNN1: drug-relation GNN layer, MI355X (gfx950).  FINAL: r19 configuration
// (best verified: 46.5 us; 104 -> 46.5 over the session).
//   prep_kernel  : b2s[k] + w2sum[n][d] + GLOBAL rela hi/lo bf16 A-frag table.
//   gnn_a4x      : ONE 512-thread block per (drug, e-half). S[r,e] = sum_d
//                  rela[r,d]*(drug[d]*W1[d,e]) via split-bf16 3-MFMA product;
//                  GEMM once per e-half; S-half[200][32] XOR-swizzled LDS;
//                  full-k b1-epilogue -> scoresA/B. rr8 + mi=0 A-frags
//                  prefetched at head; drug/w2s via direct L1-broadcast loads.
//   softgather   : softmax over K (A+B+b2s), deterministic compaction,
//                  pipelined ent gather, final linear -> y.
//   bn_kernel    : BatchNorm1d (training stats) over N=846 -> out.
// LESSONS: (r5/r8) never cap waves-per-EU below natural VGPR demand (spill
// storm); (r17) no per-block __threadfence handoff on MI355X — device-scope
// release fences serialize via cross-XCD L2 writebacks (47->410 us);
// (r15/r16/r20) fused mega-blocks, pre-split W1 tables, e-quarter splits and
// w2sum folding all lose to this split structure at this problem size.

#define NDRUG 846
#define KNB   1024
#define NREL  200
#define BN_EPS 1e-5f

#define NW2   ((NDRUG*64 + 255)/256)     // 212 w2sum blocks
#define NRELT 13312                      // 13 mt * 2 ss * 64 lane * 8 j
#define NRELB (NRELT/256)                // 52 rela-split blocks

typedef __attribute__((ext_vector_type(8))) short short8;
typedef __attribute__((ext_vector_type(4))) float f32x4;

__device__ __forceinline__ unsigned short f2bf(float x){
    unsigned u = __float_as_uint(x);
    unsigned r = u + 0x7fffu + ((u >> 16) & 1u);
    return (unsigned short)(r >> 16);
}
__device__ __forceinline__ float bf2f(unsigned short h){
    return __uint_as_float(((unsigned)h) << 16);
}

// blocks [0,4): b2 row sums; [4,4+NW2): w2sum; [.., +NRELB): rela A-frag split
__global__ void prep_kernel(const float* __restrict__ b2, const float* __restrict__ W2,
                            const float* __restrict__ rela_table,
                            float* __restrict__ b2s, float* __restrict__ w2sum_g,
                            unsigned short* __restrict__ relah,
                            unsigned short* __restrict__ relal){
    int b = blockIdx.x;
    int t = threadIdx.x;
    if (b < 4){
        int k = b*256 + t;
        const float4* p = (const float4*)(b2 + (size_t)k*64);
        float s = 0.f;
        #pragma unroll
        for (int i = 0; i < 16; ++i){ float4 v = p[i]; s += v.x+v.y+v.z+v.w; }
        b2s[k] = s;
    } else if (b < 4 + NW2){
        int idx = (b - 4)*256 + t;                     // idx = n*64 + d
        if (idx < NDRUG*64){
            const float4* p = (const float4*)(W2 + (size_t)idx*64);
            float s = 0.f;
            #pragma unroll
            for (int i = 0; i < 16; ++i){ float4 v = p[i]; s += v.x+v.y+v.z+v.w; }
            w2sum_g[idx] = s;
        }
    } else {
        // rela hi/lo split in A-fragment layout:
        // idx = ((mt*2+ss)*64 + lane)*8 + j ; row = mt*16+(lane&15) clamp 199,
        // d = ss*32 + (lane>>4)*8 + j
        int idx = (b - 4 - NW2)*256 + t;               // [0, NRELT)
        int j  = idx & 7;
        int ln = (idx >> 3) & 63;
        int ss = (idx >> 9) & 1;
        int mt = idx >> 10;
        int r = mt*16 + (ln & 15); if (r > 199) r = 199;
        int d = ss*32 + ((ln >> 4) << 3) + j;
        float v = rela_table[r*64 + d];
        unsigned short h = (unsigned short)(__float_as_uint(v) >> 16);  // trunc hi
        relah[idx] = h;
        relal[idx] = f2bf(v - bf2f(h));
    }
}

__global__ __launch_bounds__(512) void gnn_a4x(
    const float* __restrict__ drug_table, const unsigned short* __restrict__ relah,
    const unsigned short* __restrict__ relal,
    const float* __restrict__ W1,         const float* __restrict__ b1,
    const float* __restrict__ w2sum_g,    const int* __restrict__ drug_name,
    const int* __restrict__ adj_rel,
    float* __restrict__ scoresA,          float* __restrict__ scoresB)
{
    __shared__ __align__(16) float sS[6400];    // S-half[200][32], XOR-swizzled
    unsigned short* Bh = (unsigned short*)sS;          // overlay: dead after hoist
    unsigned short* Bl = (unsigned short*)(sS + 1024); // 4KB each

    const int t = threadIdx.x;
    const int lane = t & 63;
    const int w = t >> 6;                  // 8 waves
    const int lg = lane >> 4;
    const int l15 = lane & 15;
    const int n = blockIdx.x;
    const int ehalf = blockIdx.y;
    const int e_base = ehalf << 5;

    // independent global loads first: epilogue indices + mi=0 A-frags
    const int* arel = adj_rel + (size_t)n*KNB;
    int rr8[8];
    #pragma unroll
    for (int pass = 0; pass < 8; ++pass)
        rr8[pass] = arel[pass*128 + w*16 + (lane >> 2)];

    const short8* Ah_t = (const short8*)relah;
    const short8* Al_t = (const short8*)relal;
    short8 Ah0a = Ah_t[(w*2+0)*64 + lane];
    short8 Ah1a = Ah_t[(w*2+1)*64 + lane];
    short8 Al0a = Al_t[(w*2+0)*64 + lane];
    short8 Al1a = Al_t[(w*2+1)*64 + lane];

    // stage half of (drug[d]*W1[d,:]) -> hi/lo bf16, fragment-linear.
    // drug values loaded directly (16 adjacent threads share one d -> L1
    // broadcast); no LDS round-trip, no head barrier.
    {
        const int dn = drug_name[n];
        const float* drugp = drug_table + (size_t)dn*64;
        const float* W1n = W1 + (size_t)n*4096;
        #pragma unroll
        for (int p = 0; p < 4; ++p){
            int idx = p*512 + t;               // 2048 elems: d = idx>>5, eo = idx&31
            int d = idx >> 5, eo = idx & 31;
            float v = W1n[d*64 + e_base + eo] * drugp[d];
            int ss = d >> 5, j = d & 7, lgb = (d >> 3) & 3, nn = eo >> 4;
            int ln = (lgb << 4) | (eo & 15);
            int dst = (((ss<<1)|nn)*64 + ln)*8 + j;
            unsigned short h = (unsigned short)(__float_as_uint(v) >> 16);  // trunc hi
            Bh[dst] = h;
            Bl[dst] = f2bf(v - bf2f(h));
        }
    }
    __syncthreads();

    // hoist the 4 B-fragment pairs (frag-groups: ss*2+nn)
    short8 bhr[4], blr[4];
    #pragma unroll
    for (int f = 0; f < 4; ++f){
        bhr[f] = *(const short8*)&Bh[(f*64 + lane)*8];
        blr[f] = *(const short8*)&Bl[(f*64 + lane)*8];
    }
    __syncthreads();   // Bh/Bl dead; sS writable

    // GEMM mi=0 (mt = w, always valid) with prefetched A-frags
    {
        f32x4 acc[2] = {};
        #pragma unroll
        for (int nn = 0; nn < 2; ++nn){
            acc[nn] = __builtin_amdgcn_mfma_f32_16x16x32_bf16(Ah0a, bhr[nn],   acc[nn], 0,0,0);
            acc[nn] = __builtin_amdgcn_mfma_f32_16x16x32_bf16(Ah0a, blr[nn],   acc[nn], 0,0,0);
            acc[nn] = __builtin_amdgcn_mfma_f32_16x16x32_bf16(Al0a, bhr[nn],   acc[nn], 0,0,0);
            acc[nn] = __builtin_amdgcn_mfma_f32_16x16x32_bf16(Ah1a, bhr[2+nn], acc[nn], 0,0,0);
            acc[nn] = __builtin_amdgcn_mfma_f32_16x16x32_bf16(Ah1a, blr[2+nn], acc[nn], 0,0,0);
            acc[nn] = __builtin_amdgcn_mfma_f32_16x16x32_bf16(Al1a, bhr[2+nn], acc[nn], 0,0,0);
        }
        // park: word(r,eo) = r*32 + ((eo>>2 ^ (r&7))<<2) + (eo&3)
        int rb = w*16 + (lg<<2);
        #pragma unroll
        for (int nn = 0; nn < 2; ++nn){
            int eo = (nn<<4) | l15;
            int slot = eo >> 2, wrd = eo & 3;
            #pragma unroll
            for (int q = 0; q < 4; ++q){
                int r = rb + q;
                sS[r*32 + ((slot ^ (r & 7))<<2) + wrd] = acc[nn][q];  // r = w*16+.. < 128 < 200
            }
        }
    }
    // GEMM mi=1 (mt = w+8; valid for w<5)
    {
        int mt = w + 8;
        if (mt < 13){
            short8 Ah0 = Ah_t[(mt*2+0)*64 + lane];
            short8 Ah1 = Ah_t[(mt*2+1)*64 + lane];
            short8 Al0 = Al_t[(mt*2+0)*64 + lane];
            short8 Al1 = Al_t[(mt*2+1)*64 + lane];
            f32x4 acc[2] = {};
            #pragma unroll
            for (int nn = 0; nn < 2; ++nn){
                acc[nn] = __builtin_amdgcn_mfma_f32_16x16x32_bf16(Ah0, bhr[nn],   acc[nn], 0,0,0);
                acc[nn] = __builtin_amdgcn_mfma_f32_16x16x32_bf16(Ah0, blr[nn],   acc[nn], 0,0,0);
                acc[nn] = __builtin_amdgcn_mfma_f32_16x16x32_bf16(Al0, bhr[nn],   acc[nn], 0,0,0);
                acc[nn] = __builtin_amdgcn_mfma_f32_16x16x32_bf16(Ah1, bhr[2+nn], acc[nn], 0,0,0);
                acc[nn] = __builtin_amdgcn_mfma_f32_16x16x32_bf16(Ah1, blr[2+nn], acc[nn], 0,0,0);
                acc[nn] = __builtin_amdgcn_mfma_f32_16x16x32_bf16(Al1, bhr[2+nn], acc[nn], 0,0,0);
            }
            int rb = mt*16 + (lg<<2);
            #pragma unroll
            for (int nn = 0; nn < 2; ++nn){
                int eo = (nn<<4) | l15;
                int slot = eo >> 2, wrd = eo & 3;
                #pragma unroll
                for (int q = 0; q < 4; ++q){
                    int r = rb + q;
                    if (r < 200)
                        sS[r*32 + ((slot ^ (r & 7))<<2) + wrd] = acc[nn][q];
                }
            }
        }
    }
    __syncthreads();   // sS ready

    // epilogue over FULL k-range: partial score = sum_{e in half}
    // relu(S[arel[k],e] + b1[k,e]) * w2s[e];  4 lanes per k, 8 e's per lane;
    // 8 passes x 128 k per pass. w2s read directly (4 lanes share ec -> L1).
    float* sout = (ehalf ? scoresB : scoresA) + (size_t)n*KNB;
    const int ec = lane & 3;
    f32x4 w2r[2];
    #pragma unroll
    for (int j = 0; j < 2; ++j)
        w2r[j] = *(const f32x4*)(w2sum_g + n*64 + e_base + ec*8 + j*4);

    #pragma unroll 2
    for (int pass = 0; pass < 8; ++pass){
        int k = pass*128 + w*16 + (lane >> 2);
        int rr = rr8[pass];
        const float* b1p = b1 + (size_t)k*64 + e_base + ec*8;
        float sc = 0.f;
        #pragma unroll
        for (int j = 0; j < 2; ++j){
            int slot = ec*2 + j;
            f32x4 s4 = *(const f32x4*)&sS[rr*32 + ((slot ^ (rr & 7))<<2)];
            f32x4 bq = *(const f32x4*)(b1p + 4*j);
            #pragma unroll
            for (int q = 0; q < 4; ++q)
                sc += fmaxf(s4[q] + bq[q], 0.f) * w2r[j][q];
        }
        sc += __shfl_xor(sc, 1);
        sc += __shfl_xor(sc, 2);
        if (ec == 0) sout[k] = sc;
    }
}

__global__ __launch_bounds__(256,6) void softgather(
    const float* __restrict__ scoresA,  const float* __restrict__ scoresB,
    const float* __restrict__ b2s,
    const int* __restrict__ adj_tail,   const float* __restrict__ ent_table,
    const float* __restrict__ drug_table, const int* __restrict__ drug_name,
    const float* __restrict__ lin_w,    const float* __restrict__ lin_b,
    float* __restrict__ y_out)
{
    __shared__ float sE[KNB];
    __shared__ int list[KNB];
    __shared__ int segc[17];
    __shared__ float red[256];
    __shared__ float wepart[4][64];
    __shared__ float de[128];

    const int t = threadIdx.x;
    const int lane = t & 63;
    const int w = t >> 6;
    const int n = blockIdx.x;

    float dpre = 0.f;
    if (t < 64) dpre = drug_table[(size_t)drug_name[n]*64 + t];

    const float* sgA = scoresA + (size_t)n*KNB;
    const float* sgB = scoresB + (size_t)n*KNB;
    float sv[4]; float mx = -1e30f;
    #pragma unroll
    for (int i = 0; i < 4; ++i){
        int k = t + (i<<8);
        sv[i] = sgA[k] + sgB[k] + b2s[k];
        mx = fmaxf(mx, sv[i]);
    }
    #pragma unroll
    for (int off = 1; off < 64; off <<= 1) mx = fmaxf(mx, __shfl_xor(mx, off, 64));
    if (lane == 0) red[w] = mx;
    __syncthreads();
    mx = fmaxf(fmaxf(red[0], red[1]), fmaxf(red[2], red[3]));
    float ei[4]; float ps = 0.f;
    #pragma unroll
    for (int i = 0; i < 4; ++i){
        ei[i] = __expf(sv[i] - mx);
        sE[t + (i<<8)] = ei[i];
        ps += ei[i];
    }
    #pragma unroll
    for (int off = 1; off < 64; off <<= 1) ps += __shfl_xor(ps, off, 64);
    if (lane == 0) red[8 + w] = ps;
    __syncthreads();
    const float inv = 1.f / (red[8]+red[9]+red[10]+red[11]);

    // deterministic compaction of nonzero-weight k's (ordered by k)
    unsigned long long bal[4]; int pos[4];
    #pragma unroll
    for (int i = 0; i < 4; ++i){
        bool nz = (ei[i] != 0.f);
        bal[i] = __ballot(nz);
        pos[i] = (int)__popcll(bal[i] & ((1ull << lane) - 1ull));
        if (lane == 0) segc[i*4 + w] = (int)__popcll(bal[i]);
    }
    __syncthreads();
    if (t == 0){
        int acc = 0;
        #pragma unroll
        for (int s = 0; s < 16; ++s){ int c = segc[s]; segc[s] = acc; acc += c; }
        segc[16] = acc;
    }
    __syncthreads();
    #pragma unroll
    for (int i = 0; i < 4; ++i){
        if (ei[i] != 0.f)
            list[segc[i*4 + w] + pos[i]] = (i<<8) + (w<<6) + lane;
    }
    const int C = segc[16];
    __syncthreads();

    // pipelined gather over compacted list (wave-strided)
    const int* atail = adj_tail + (size_t)n*KNB;
    float awe = 0.f;
    {
        int j = w;
        float ev0 = 0.f, row0 = 0.f;
        if (j < C){
            int k0 = list[j];
            ev0 = sE[k0];
            row0 = ent_table[(size_t)atail[k0]*64 + lane];
        }
        while (j < C){
            int jn = j + 4;
            float ev1 = 0.f, row1 = 0.f;
            if (jn < C){
                int k1 = list[jn];
                ev1 = sE[k1];
                row1 = ent_table[(size_t)atail[k1]*64 + lane];
            }
            awe += ev0 * row0;
            ev0 = ev1; row0 = row1; j = jn;
        }
    }
    wepart[w][lane] = awe;
    __syncthreads();
    if (t < 64){
        de[t]    = (wepart[0][t]+wepart[1][t]+wepart[2][t]+wepart[3][t]) * inv;
        de[64+t] = dpre;
    }
    __syncthreads();

    float yp = 0.f;
    #pragma unroll
    for (int ii = 0; ii < 32; ++ii){
        int i = w*32 + ii;
        yp += de[i] * lin_w[lane*128 + i];
    }
    red[t] = yp;
    __syncthreads();
    if (t < 64){
        float yv = lin_b[t] + red[t] + red[64+t] + red[128+t] + red[192+t];
        y_out[(size_t)n*64 + t] = fmaxf(yv, 0.f);
    }
}

__global__ void bn_kernel(const float* __restrict__ y, const float* __restrict__ bn_w,
                          const float* __restrict__ bn_b, float* __restrict__ out){
    __shared__ float r1[4], r2[4];
    const int j = blockIdx.x;
    const int t = threadIdx.x;
    float s1 = 0.f, s2 = 0.f;
    for (int i = t; i < NDRUG; i += 256){
        float v = y[(size_t)i*64 + j];
        s1 += v; s2 += v*v;
    }
    #pragma unroll
    for (int off = 1; off < 64; off <<= 1){
        s1 += __shfl_xor(s1, off, 64);
        s2 += __shfl_xor(s2, off, 64);
    }
    int w = t >> 6, lane = t & 63;
    if (lane == 0){ r1[w] = s1; r2[w] = s2; }
    __syncthreads();
    s1 = r1[0]+r1[1]+r1[2]+r1[3];
    s2 = r2[0]+r2[1]+r2[2]+r2[3];
    float mean = s1 * (1.f/NDRUG);
    float var  = s2 * (1.f/NDRUG) - mean*mean;   // biased (training-mode) variance
    float sc = rsqrtf(var + BN_EPS) * bn_w[j];
    float sh = bn_b[j] - mean*sc;
    for (int i = t; i < NDRUG; i += 256)
        out[(size_t)i*64 + j] = y[(size_t)i*64 + j]*sc + sh;
}

extern "C" void kernel_launch(void* const* d_in, const int* in_sizes, int n_in,
                              void* d_out, int out_size, void* d_ws, size_t ws_size,
                              hipStream_t stream) {
    const float* drug_table = (const float*)d_in[0];
    const float* rela_table = (const float*)d_in[1];
    const float* ent_table  = (const float*)d_in[2];
    const float* W1    = (const float*)d_in[3];
    const float* b1    = (const float*)d_in[4];
    const float* W2    = (const float*)d_in[5];
    const float* b2    = (const float*)d_in[6];
    const float* lin_w = (const float*)d_in[7];
    const float* lin_b = (const float*)d_in[8];
    const float* bn_w  = (const float*)d_in[9];
    const float* bn_b  = (const float*)d_in[10];
    const int* drug_name = (const int*)d_in[11];
    const int* adj_tail  = (const int*)d_in[12];
    const int* adj_rel   = (const int*)d_in[13];
    float* out = (float*)d_out;

    float* b2s     = (float*)d_ws;                  // [1024]
    float* yb      = b2s + KNB;                     // [846*64]
    float* w2sumg  = yb + NDRUG*64;                 // [846*64]
    float* scoresA = w2sumg + NDRUG*64;             // [846*1024]
    float* scoresB = scoresA + (size_t)NDRUG*KNB;   // [846*1024]
    unsigned short* relah = (unsigned short*)(scoresB + (size_t)NDRUG*KNB); // [13312]
    unsigned short* relal = relah + NRELT;                                  // [13312]

    prep_kernel<<<4 + NW2 + NRELB, 256, 0, stream>>>(
        b2, W2, rela_table, b2s, w2sumg, relah, relal);
    gnn_a4x<<<dim3(NDRUG,2), 512, 0, stream>>>(drug_table, relah, relal, W1, b1,
                                               w2sumg, drug_name, adj_rel,
                                               scoresA, scoresB);
    softgather<<<NDRUG, 256, 0, stream>>>(scoresA, scoresB, b2s, adj_tail, ent_table,
                                          drug_table, drug_name, lin_w, lin_b, yb);
    bn_kernel<<<64, 256, 0, stream>>>(yb, bn_w, bn_b, out);
}